// Round 8
// baseline (78.322 us; speedup 1.0000x reference)
//
#include <hip/hip_runtime.h>
#include <hip/hip_bf16.h>
#include <stdint.h>

#define N_TOK   4096
#define TOPK    2
#define NSORT   (N_TOK * TOPK)   // 8192
#define NEXP    8
#define DIM     1024

#define BM 128
#define BN 64
#define BK 64

typedef __attribute__((ext_vector_type(8))) short bfrag;    // 8 bf16 = 4 VGPR (MFMA A/B operand)
typedef __attribute__((ext_vector_type(4))) float f32x4;    // MFMA C/D

static __device__ __forceinline__ unsigned short f2bf(float f) {
  __hip_bfloat16 h = __float2bfloat16(f);
  return __builtin_bit_cast(unsigned short, h);
}
static __device__ __forceinline__ float bf2f(unsigned short u) {
  unsigned int v = ((unsigned int)u) << 16;
  return __builtin_bit_cast(float, v);
}

// async global->LDS, 16B per lane; lds base must be wave-uniform (HW writes base + lane*16)
static __device__ __forceinline__ void gload16(void* lds_base, const void* gsrc) {
  __builtin_amdgcn_global_load_lds(
      (const __attribute__((address_space(1))) void*)gsrc,
      (__attribute__((address_space(3))) void*)lds_base, 16, 0, 0);
}

// ---------------- kernel 1: gather x rows into sorted order, cvt to bf16 ----------------
__global__ __launch_bounds__(256) void k_gather_x(
    const float* __restrict__ x, const int* __restrict__ ssi, const int* __restrict__ kp,
    unsigned short* __restrict__ xg, float* __restrict__ zbuf)
{
  const int row = blockIdx.x;          // 0..NSORT-1
  const int t = threadIdx.x;           // 256 threads, 4 floats each
  const int kk = kp[0];
  const int tok = ssi[row] / kk;
  float4 v = ((const float4*)(x + (size_t)tok * DIM))[t];
  ushort4 o;
  o.x = f2bf(v.x); o.y = f2bf(v.y); o.z = f2bf(v.z); o.w = f2bf(v.w);
  ((ushort4*)(xg + (size_t)row * DIM))[t] = o;
  if (row == 0) { zbuf[t] = 0.0f; zbuf[256 + t] = 0.0f; }   // 2KB zero page (masked staging)
}

// ---------------- kernel 2: W [e][k][n] fp32 -> WT [e][n][k] bf16 (LDS-tiled transpose) ---
__global__ __launch_bounds__(256) void k_transp_w(
    const float* __restrict__ W, unsigned short* __restrict__ WT)
{
  __shared__ float tile[64][65];
  const int nb = blockIdx.x;   // 16
  const int kb = blockIdx.y;   // 16
  const int e  = blockIdx.z;   // 8
  const int t = threadIdx.x;
  const float* src = W + (((size_t)e * DIM) + (size_t)kb * 64) * DIM + nb * 64;
  #pragma unroll
  for (int p = 0; p < 4; ++p) {
    int q = p * 256 + t;       // 0..1023 float4-units
    int i = q >> 4;            // k-row 0..63
    int j4 = q & 15;           // float4 within row
    float4 v = *(const float4*)(src + (size_t)i * DIM + j4 * 4);
    tile[i][j4 * 4 + 0] = v.x; tile[i][j4 * 4 + 1] = v.y;
    tile[i][j4 * 4 + 2] = v.z; tile[i][j4 * 4 + 3] = v.w;
  }
  __syncthreads();
  unsigned short* dst = WT + (((size_t)e * DIM) + (size_t)nb * 64) * DIM + kb * 64;
  #pragma unroll
  for (int p = 0; p < 4; ++p) {
    int q = p * 256 + t;
    int j = q >> 4;            // n-row 0..63
    int i4 = q & 15;           // k float4
    ushort4 o;
    o.x = f2bf(tile[i4 * 4 + 0][j]);
    o.y = f2bf(tile[i4 * 4 + 1][j]);
    o.z = f2bf(tile[i4 * 4 + 2][j]);
    o.w = f2bf(tile[i4 * 4 + 3][j]);
    *(ushort4*)(dst + (size_t)j * DIM + i4 * 4) = o;
  }
}

// -- kernel 3: grouped GEMM, 128x64 tile, 3-deep counted-vmcnt pipeline (T4), raw barriers
__global__ __launch_bounds__(256, 2) void k_moe_gemm(
    const unsigned short* __restrict__ xg,   // [NSORT][DIM] bf16 (sorted order)
    const unsigned short* __restrict__ WT,   // [NEXP][DIM n][DIM k] bf16
    const int* __restrict__ sei, const int* __restrict__ ssi,
    const float* __restrict__ zbuf,
    unsigned short* __restrict__ outw)       // [NSORT][DIM] bf16, rows at flat-slot index
{
  __shared__ char lds[3][(BM + BN) * BK * 2];   // 3 x 24KB (A 16KB then B 8KB per buffer)
  __shared__ int s_sei[BM];
  __shared__ int s_ssi[BM];

  // XCD-aware bijective swizzle (nwg=1024, 1024%8==0): each XCD gets a contiguous
  // 128-block chunk; ct-fastest decode -> 16 ct-blocks sharing one A-tile stay in-XCD.
  const int swz = (blockIdx.x & 7) * 128 + (blockIdx.x >> 3);
  const int rt = swz >> 4;             // 0..63 row tile
  const int ct = swz & 15;             // 0..15 col tile
  const int t = threadIdx.x;
  const int lane = t & 63;
  const int w = t >> 6;                // 4 waves, 2M x 2N (64x32 tile each)
  const int wr = w >> 1;
  const int wc = w & 1;

  if (t < BM) {
    s_sei[t] = sei[rt * BM + t];
    s_ssi[t] = ssi[rt * BM + t];
  }
  __syncthreads();

  const int e0 = s_sei[0];
  const int e1 = s_sei[BM - 1];
  const int nsteps = (e1 - e0 + 1) * (DIM / BK);

  f32x4 acc[4][2];
  #pragma unroll
  for (int m = 0; m < 4; ++m)
    #pragma unroll
    for (int n = 0; n < 2; ++n)
      acc[m][n] = (f32x4){0.f, 0.f, 0.f, 0.f};

  const int g = lane >> 4;
  const int r = lane & 15;

  // staging geometry (rule 21: linear LDS dest, inverse-swizzled global source)
  // A: 16 chunks of 1KB, wave owns 4w..4w+3;  B: 8 chunks, wave owns 2w..2w+1
  int rA[4], kA[4], rB[2], kB[2];
  #pragma unroll
  for (int i = 0; i < 4; ++i) {
    int o = (4 * w + i) * 1024 + lane * 16;
    int osw = o ^ (((o >> 7) & 7) << 4);
    rA[i] = osw >> 7; kA[i] = osw & 127;
  }
  #pragma unroll
  for (int i = 0; i < 2; ++i) {
    int o = (2 * w + i) * 1024 + lane * 16;
    int osw = o ^ (((o >> 7) & 7) << 4);
    rB[i] = osw >> 7; kB[i] = osw & 127;   // n-row 0..63
  }

  // per-expert hoisted source bases (per-lane); masked A rows point at the 2KB zero page
  const char *ap[4], *bp[2];
  int ecur = 0x7fffffff;
  auto setup = [&](int e) {
    #pragma unroll
    for (int i = 0; i < 4; ++i)
      ap[i] = (s_sei[rA[i]] == e)
          ? (const char*)(xg + ((size_t)(rt * BM + rA[i])) * DIM) + kA[i] : (const char*)zbuf;
    #pragma unroll
    for (int i = 0; i < 2; ++i)
      bp[i] = (const char*)(WT + (((size_t)e * DIM) + ct * BN + rB[i]) * DIM) + kB[i];
  };
  auto stage = [&](int s, int b) {
    const int e = e0 + (s >> 4);
    if (e != ecur) { ecur = e; setup(e); }   // wave-uniform, fires ~1.1x per block
    const int koff = (s & 15) * 128;         // bytes along k (zero page is 2KB: +koff safe)
    char* base = (char*)lds[b];
    #pragma unroll
    for (int i = 0; i < 4; ++i)
      gload16(base + (4 * w + i) * 1024, ap[i] + koff);       // 6 loads/wave per stage
    #pragma unroll
    for (int i = 0; i < 2; ++i)
      gload16(base + 16384 + (2 * w + i) * 1024, bp[i] + koff);
  };

  // prologue: fill the 3-deep pipeline (18 loads/wave in flight)
  stage(0, 0); stage(1, 1); stage(2, 2);

  int cur = 0;
  for (int s = 0; s < nsteps; ++s) {
    // wait ONLY for stage s (oldest 6 of 18) — stages s+1, s+2 stay in flight (T4)
    asm volatile("s_waitcnt vmcnt(12)" ::: "memory");
    __builtin_amdgcn_s_barrier();            // all waves' stage-s data in LDS
    __builtin_amdgcn_sched_barrier(0);       // pin: no ds_read hoists above barrier

    const char* pA = (const char*)lds[cur];
    const char* pB = (const char*)lds[cur] + 16384;
    #pragma unroll
    for (int kh = 0; kh < 2; ++kh) {
      const int kbyte = (kh * 32 + 8 * g) * 2;   // same k-slot for A and B (positional symmetry)
      bfrag af[4], bfv[2];
      #pragma unroll
      for (int m = 0; m < 4; ++m) {
        const int row = wr * 64 + m * 16 + r;
        int o = (row << 7) + kbyte;
        o ^= ((row & 7) << 4);
        af[m] = *(const bfrag*)(pA + o);
      }
      #pragma unroll
      for (int n = 0; n < 2; ++n) {
        const int nn = wc * 32 + n * 16 + r;
        int o = (nn << 7) + kbyte;
        o ^= ((nn & 7) << 4);
        bfv[n] = *(const bfrag*)(pB + o);
      }
      #pragma unroll
      for (int m = 0; m < 4; ++m)
        #pragma unroll
        for (int n = 0; n < 2; ++n)
          acc[m][n] = __builtin_amdgcn_mfma_f32_16x16x32_bf16(af[m], bfv[n], acc[m][n], 0, 0, 0);
    }

    asm volatile("s_waitcnt lgkmcnt(0)" ::: "memory");   // all my ds_reads of buf done
    __builtin_amdgcn_s_barrier();            // all waves done reading buf cur
    __builtin_amdgcn_sched_barrier(0);       // pin: no gload sinks above this point

    int sn = s + 3;                          // refill freed buffer with step s+3
    if (sn > nsteps - 1) sn = nsteps - 1;    // tail: dummy re-stage (never consumed), keeps
    stage(sn, cur);                          //   vmcnt(12) a compile-time constant
    cur = (cur == 2) ? 0 : cur + 1;
  }

  // epilogue: C/D map col = lane&15, row = (lane>>4)*4 + reg; scatter rows by ssi (bf16)
  #pragma unroll
  for (int m = 0; m < 4; ++m) {
    #pragma unroll
    for (int q = 0; q < 4; ++q) {
      const int rl = wr * 64 + m * 16 + g * 4 + q;
      const int orow = s_ssi[rl];
      unsigned short* od = outw + (size_t)orow * DIM + ct * BN + wc * 32 + r;
      #pragma unroll
      for (int n = 0; n < 2; ++n)
        od[n * 16] = f2bf(acc[m][n][q]);
    }
  }
}

// ---------------- kernel 4: gate-weighted pair combine -> fp32 out ----------------------
__global__ __launch_bounds__(256) void k_combine(
    const unsigned short* __restrict__ outw, const float* __restrict__ gates,
    const int* __restrict__ kp, float* __restrict__ out)
{
  const int tk = blockIdx.x;     // token
  const int t = threadIdx.x;     // 256 threads x 4 floats
  const int kk = kp[0];
  float4 o = {0.f, 0.f, 0.f, 0.f};
  for (int s = 0; s < kk; ++s) {
    const float gte = gates[tk * kk + s];
    ushort4 a = ((const ushort4*)(outw + ((size_t)tk * kk + s) * DIM))[t];
    o.x += gte * bf2f(a.x);
    o.y += gte * bf2f(a.y);
    o.z += gte * bf2f(a.z);
    o.w += gte * bf2f(a.w);
  }
  ((float4*)(out + (size_t)tk * DIM))[t] = o;
}

extern "C" void kernel_launch(void* const* d_in, const int* in_sizes, int n_in,
                              void* d_out, int out_size, void* d_ws, size_t ws_size,
                              hipStream_t stream)
{
  const float* x     = (const float*)d_in[0];
  const float* W     = (const float*)d_in[1];
  const float* gates = (const float*)d_in[2];
  const int* kp      = (const int*)d_in[3];
  const int* sei     = (const int*)d_in[4];
  const int* ssi     = (const int*)d_in[5];
  // d_in[6] padded_block_idxs, d_in[7] expert_offsets: not needed (masked pass loop)

  const size_t MB = 1024 * 1024;
  if (ws_size < 48 * MB + 4096) return;   // 48MB scratch + 2KB zero page

  char* ws = (char*)d_ws;
  unsigned short* xg   = (unsigned short*)(ws);              // 16 MB: bf16 gathered x
  unsigned short* WT   = (unsigned short*)(ws + 16 * MB);    // 16 MB: bf16 W^T
  unsigned short* outw = (unsigned short*)(ws + 32 * MB);    // 16 MB: bf16 out_flat
  float* zbuf          = (float*)(ws + 48 * MB);             // 2 KB zero page

  k_gather_x<<<NSORT, 256, 0, stream>>>(x, ssi, kp, xg, zbuf);
  k_transp_w<<<dim3(16, 16, 8), 256, 0, stream>>>(W, WT);
  k_moe_gemm<<<(NSORT / BM) * (DIM / BN), 256, 0, stream>>>(xg, WT, sei, ssi, zbuf, outw);
  k_combine<<<N_TOK, 256, 0, stream>>>(outw, gates, kp, (float*)d_out);
}

// Round 9
// 63.433 us; speedup vs baseline: 1.2347x; 1.2347x over previous
//
#include <hip/hip_runtime.h>
#include <hip/hip_bf16.h>
#include <stdint.h>

#define N_TOK   4096
#define TOPK    2
#define NSORT   (N_TOK * TOPK)   // 8192
#define NEXP    8
#define DIM     1024

#define BM 128
#define BN 64
#define BK 64

typedef __attribute__((ext_vector_type(8))) short bfrag;    // 8 bf16 = 4 VGPR (MFMA A/B operand)
typedef __attribute__((ext_vector_type(4))) float f32x4;    // MFMA C/D

static __device__ __forceinline__ unsigned short f2bf(float f) {
  __hip_bfloat16 h = __float2bfloat16(f);
  return __builtin_bit_cast(unsigned short, h);
}
static __device__ __forceinline__ float bf2f(unsigned short u) {
  unsigned int v = ((unsigned int)u) << 16;
  return __builtin_bit_cast(float, v);
}

// async global->LDS, 16B per lane; lds base must be wave-uniform (HW writes base + lane*16)
static __device__ __forceinline__ void gload16(void* lds_base, const void* gsrc) {
  __builtin_amdgcn_global_load_lds(
      (const __attribute__((address_space(1))) void*)gsrc,
      (__attribute__((address_space(3))) void*)lds_base, 16, 0, 0);
}

// ---------------- kernel 1: gather x rows into sorted order, cvt to bf16 ----------------
__global__ __launch_bounds__(256) void k_gather_x(
    const float* __restrict__ x, const int* __restrict__ ssi, const int* __restrict__ kp,
    unsigned short* __restrict__ xg, float* __restrict__ zbuf)
{
  const int row = blockIdx.x;          // 0..NSORT-1
  const int t = threadIdx.x;           // 256 threads, 4 floats each
  const int kk = kp[0];
  const int tok = ssi[row] / kk;
  float4 v = ((const float4*)(x + (size_t)tok * DIM))[t];
  ushort4 o;
  o.x = f2bf(v.x); o.y = f2bf(v.y); o.z = f2bf(v.z); o.w = f2bf(v.w);
  ((ushort4*)(xg + (size_t)row * DIM))[t] = o;
  if (row == 0) { zbuf[t] = 0.0f; zbuf[256 + t] = 0.0f; }   // 2KB zero page (masked staging)
}

// ---------------- kernel 2: W [e][k][n] fp32 -> WT [e][n][k] bf16 (LDS-tiled transpose) ---
__global__ __launch_bounds__(256) void k_transp_w(
    const float* __restrict__ W, unsigned short* __restrict__ WT)
{
  __shared__ float tile[64][65];
  const int nb = blockIdx.x;   // 16
  const int kb = blockIdx.y;   // 16
  const int e  = blockIdx.z;   // 8
  const int t = threadIdx.x;
  const float* src = W + (((size_t)e * DIM) + (size_t)kb * 64) * DIM + nb * 64;
  #pragma unroll
  for (int p = 0; p < 4; ++p) {
    int q = p * 256 + t;       // 0..1023 float4-units
    int i = q >> 4;            // k-row 0..63
    int j4 = q & 15;           // float4 within row
    float4 v = *(const float4*)(src + (size_t)i * DIM + j4 * 4);
    tile[i][j4 * 4 + 0] = v.x; tile[i][j4 * 4 + 1] = v.y;
    tile[i][j4 * 4 + 2] = v.z; tile[i][j4 * 4 + 3] = v.w;
  }
  __syncthreads();
  unsigned short* dst = WT + (((size_t)e * DIM) + (size_t)nb * 64) * DIM + kb * 64;
  #pragma unroll
  for (int p = 0; p < 4; ++p) {
    int q = p * 256 + t;
    int j = q >> 4;            // n-row 0..63
    int i4 = q & 15;           // k float4
    ushort4 o;
    o.x = f2bf(tile[i4 * 4 + 0][j]);
    o.y = f2bf(tile[i4 * 4 + 1][j]);
    o.z = f2bf(tile[i4 * 4 + 2][j]);
    o.w = f2bf(tile[i4 * 4 + 3][j]);
    *(ushort4*)(dst + (size_t)j * DIM + i4 * 4) = o;
  }
}

// -- kernel 3: grouped GEMM, 128x64 tile, 2 waves x (64x64 sub-tile), r7 loop structure ---
__global__ __launch_bounds__(128, 3) void k_moe_gemm(
    const unsigned short* __restrict__ xg,   // [NSORT][DIM] bf16 (sorted order)
    const unsigned short* __restrict__ WT,   // [NEXP][DIM n][DIM k] bf16
    const int* __restrict__ sei, const int* __restrict__ ssi,
    const float* __restrict__ zbuf,
    unsigned short* __restrict__ outw)       // [NSORT][DIM] bf16, rows at flat-slot index
{
  __shared__ unsigned short lA[BM * BK];   // 16 KB
  __shared__ unsigned short lB[BN * BK];   // 8 KB
  __shared__ int s_sei[BM];
  __shared__ int s_ssi[BM];

  // XCD-aware bijective swizzle (nwg=1024, 1024%8==0): each XCD gets a contiguous
  // 128-block chunk; ct-fastest decode -> 16 ct-blocks sharing one A-tile stay in-XCD.
  const int swz = (blockIdx.x & 7) * 128 + (blockIdx.x >> 3);
  const int rt = swz >> 4;             // 0..63 row tile
  const int ct = swz & 15;             // 0..15 col tile
  const int t = threadIdx.x;           // 128 threads = 2 waves
  const int lane = t & 63;
  const int w = t >> 6;                // wave 0: rows 0..63, wave 1: rows 64..127; full 64 cols

  s_sei[t] = sei[rt * BM + t];         // 128 threads cover BM exactly
  s_ssi[t] = ssi[rt * BM + t];
  __syncthreads();

  const int e0 = s_sei[0];
  const int e1 = s_sei[BM - 1];
  const int nsteps = (e1 - e0 + 1) * (DIM / BK);

  f32x4 acc[4][4];
  #pragma unroll
  for (int m = 0; m < 4; ++m)
    #pragma unroll
    for (int n = 0; n < 4; ++n)
      acc[m][n] = (f32x4){0.f, 0.f, 0.f, 0.f};

  const int g = lane >> 4;
  const int r = lane & 15;

  // staging geometry (rule 21: linear LDS dest, inverse-swizzled global source)
  // A: 16 chunks of 1KB, wave owns 8w..8w+7;  B: 8 chunks, wave owns 4w..4w+3
  int rA[8], kA[8], rB[4], kB[4];
  #pragma unroll
  for (int i = 0; i < 8; ++i) {
    int o = (8 * w + i) * 1024 + lane * 16;
    int osw = o ^ (((o >> 7) & 7) << 4);
    rA[i] = osw >> 7; kA[i] = osw & 127;
  }
  #pragma unroll
  for (int i = 0; i < 4; ++i) {
    int o = (4 * w + i) * 1024 + lane * 16;
    int osw = o ^ (((o >> 7) & 7) << 4);
    rB[i] = osw >> 7; kB[i] = osw & 127;   // n-row 0..63
  }

  // per-expert hoisted source bases (per-lane); masked A rows point at the 2KB zero page
  const char *ap[8], *bp[4];
  int ecur = 0x7fffffff;
  auto setup = [&](int e) {
    #pragma unroll
    for (int i = 0; i < 8; ++i)
      ap[i] = (s_sei[rA[i]] == e)
          ? (const char*)(xg + ((size_t)(rt * BM + rA[i])) * DIM) + kA[i] : (const char*)zbuf;
    #pragma unroll
    for (int i = 0; i < 4; ++i)
      bp[i] = (const char*)(WT + (((size_t)e * DIM) + ct * BN + rB[i]) * DIM) + kB[i];
  };
  auto stage = [&](int s) {
    const int e = e0 + (s >> 4);
    if (e != ecur) { ecur = e; setup(e); }   // wave-uniform, fires ~1.1x per block
    const int koff = (s & 15) * 128;         // bytes along k (zero page is 2KB: +koff safe)
    #pragma unroll
    for (int i = 0; i < 8; ++i)
      gload16((char*)lA + (8 * w + i) * 1024, ap[i] + koff);
    #pragma unroll
    for (int i = 0; i < 4; ++i)
      gload16((char*)lB + (4 * w + i) * 1024, bp[i] + koff);
  };

  for (int s = 0; s < nsteps; ++s) {
    stage(s);
    __syncthreads();   // vmcnt(0) drain + barrier (cross-block TLP hides it at 4-6 blk/CU)
    #pragma unroll
    for (int kh = 0; kh < 2; ++kh) {
      const int kbyte = (kh * 32 + 8 * g) * 2;   // same k-slot for A and B (positional symmetry)
      bfrag af[4], bfv[4];
      #pragma unroll
      for (int m = 0; m < 4; ++m) {
        const int row = w * 64 + m * 16 + r;
        int o = (row << 7) + kbyte;
        o ^= ((row & 7) << 4);
        af[m] = *(const bfrag*)((const char*)lA + o);
      }
      #pragma unroll
      for (int n = 0; n < 4; ++n) {
        const int nn = n * 16 + r;
        int o = (nn << 7) + kbyte;
        o ^= ((nn & 7) << 4);
        bfv[n] = *(const bfrag*)((const char*)lB + o);
      }
      #pragma unroll
      for (int m = 0; m < 4; ++m)
        #pragma unroll
        for (int n = 0; n < 4; ++n)
          acc[m][n] = __builtin_amdgcn_mfma_f32_16x16x32_bf16(af[m], bfv[n], acc[m][n], 0, 0, 0);
    }
    __syncthreads();   // compute done before next stage overwrites LDS
  }

  // epilogue: C/D map col = lane&15, row = (lane>>4)*4 + reg; scatter rows by ssi (bf16)
  #pragma unroll
  for (int m = 0; m < 4; ++m) {
    #pragma unroll
    for (int q = 0; q < 4; ++q) {
      const int rl = w * 64 + m * 16 + g * 4 + q;
      const int orow = s_ssi[rl];
      unsigned short* od = outw + (size_t)orow * DIM + ct * BN + r;
      #pragma unroll
      for (int n = 0; n < 4; ++n)
        od[n * 16] = f2bf(acc[m][n][q]);
    }
  }
}

// ---------------- kernel 4: gate-weighted pair combine -> fp32 out ----------------------
__global__ __launch_bounds__(256) void k_combine(
    const unsigned short* __restrict__ outw, const float* __restrict__ gates,
    const int* __restrict__ kp, float* __restrict__ out)
{
  const int tk = blockIdx.x;     // token
  const int t = threadIdx.x;     // 256 threads x 4 floats
  const int kk = kp[0];
  float4 o = {0.f, 0.f, 0.f, 0.f};
  for (int s = 0; s < kk; ++s) {
    const float gte = gates[tk * kk + s];
    ushort4 a = ((const ushort4*)(outw + ((size_t)tk * kk + s) * DIM))[t];
    o.x += gte * bf2f(a.x);
    o.y += gte * bf2f(a.y);
    o.z += gte * bf2f(a.z);
    o.w += gte * bf2f(a.w);
  }
  ((float4*)(out + (size_t)tk * DIM))[t] = o;
}

extern "C" void kernel_launch(void* const* d_in, const int* in_sizes, int n_in,
                              void* d_out, int out_size, void* d_ws, size_t ws_size,
                              hipStream_t stream)
{
  const float* x     = (const float*)d_in[0];
  const float* W     = (const float*)d_in[1];
  const float* gates = (const float*)d_in[2];
  const int* kp      = (const int*)d_in[3];
  const int* sei     = (const int*)d_in[4];
  const int* ssi     = (const int*)d_in[5];
  // d_in[6] padded_block_idxs, d_in[7] expert_offsets: not needed (masked pass loop)

  const size_t MB = 1024 * 1024;
  if (ws_size < 48 * MB + 4096) return;   // 48MB scratch + 2KB zero page

  char* ws = (char*)d_ws;
  unsigned short* xg   = (unsigned short*)(ws);              // 16 MB: bf16 gathered x
  unsigned short* WT   = (unsigned short*)(ws + 16 * MB);    // 16 MB: bf16 W^T
  unsigned short* outw = (unsigned short*)(ws + 32 * MB);    // 16 MB: bf16 out_flat
  float* zbuf          = (float*)(ws + 48 * MB);             // 2 KB zero page

  k_gather_x<<<NSORT, 256, 0, stream>>>(x, ssi, kp, xg, zbuf);
  k_transp_w<<<dim3(16, 16, 8), 256, 0, stream>>>(W, WT);
  k_moe_gemm<<<(NSORT / BM) * (DIM / BN), 128, 0, stream>>>(xg, WT, sei, ssi, zbuf, outw);
  k_combine<<<N_TOK, 256, 0, stream>>>(outw, gates, kp, (float*)d_out);
}

// Round 10
// 60.504 us; speedup vs baseline: 1.2945x; 1.0484x over previous
//
#include <hip/hip_runtime.h>
#include <hip/hip_bf16.h>
#include <stdint.h>

#define N_TOK   4096
#define TOPK    2
#define NSORT   (N_TOK * TOPK)   // 8192
#define NEXP    8
#define DIM     1024

#define BM 128
#define BN 128
#define BK 64

typedef __attribute__((ext_vector_type(8))) short bfrag;    // 8 bf16 = 4 VGPR (MFMA A/B operand)
typedef __attribute__((ext_vector_type(4))) float f32x4;    // MFMA C/D

static __device__ __forceinline__ unsigned short f2bf(float f) {
  __hip_bfloat16 h = __float2bfloat16(f);
  return __builtin_bit_cast(unsigned short, h);
}
static __device__ __forceinline__ float bf2f(unsigned short u) {
  unsigned int v = ((unsigned int)u) << 16;
  return __builtin_bit_cast(float, v);
}

// async global->LDS, 16B per lane; lds base must be wave-uniform (HW writes base + lane*16)
static __device__ __forceinline__ void gload16(void* lds_base, const void* gsrc) {
  __builtin_amdgcn_global_load_lds(
      (const __attribute__((address_space(1))) void*)gsrc,
      (__attribute__((address_space(3))) void*)lds_base, 16, 0, 0);
}

// ---------------- kernel 1: straight cast x fp32 -> bf16 (token order; no gather) -------
__global__ __launch_bounds__(256) void k_prep(
    const float* __restrict__ x, unsigned short* __restrict__ xb, float* __restrict__ zbuf)
{
  const size_t i = ((size_t)blockIdx.x * 256 + threadIdx.x) * 8;   // 8 floats/thread
  float4 a = *(const float4*)(x + i);
  float4 b = *(const float4*)(x + i + 4);
  ushort4 oa, ob;
  oa.x = f2bf(a.x); oa.y = f2bf(a.y); oa.z = f2bf(a.z); oa.w = f2bf(a.w);
  ob.x = f2bf(b.x); ob.y = f2bf(b.y); ob.z = f2bf(b.z); ob.w = f2bf(b.w);
  *(ushort4*)(xb + i) = oa;
  *(ushort4*)(xb + i + 4) = ob;
  if (blockIdx.x == 0) { zbuf[threadIdx.x] = 0.f; zbuf[256 + threadIdx.x] = 0.f; }  // 2KB zero page
}

// ---------------- kernel 2: W [e][k][n] fp32 -> WT [e][n][k] bf16 (LDS-tiled transpose) ---
__global__ __launch_bounds__(256) void k_transp_w(
    const float* __restrict__ W, unsigned short* __restrict__ WT)
{
  __shared__ float tile[64][65];
  const int nb = blockIdx.x;   // 16
  const int kb = blockIdx.y;   // 16
  const int e  = blockIdx.z;   // 8
  const int t = threadIdx.x;
  const float* src = W + (((size_t)e * DIM) + (size_t)kb * 64) * DIM + nb * 64;
  #pragma unroll
  for (int p = 0; p < 4; ++p) {
    int q = p * 256 + t;       // 0..1023 float4-units
    int i = q >> 4;            // k-row 0..63
    int j4 = q & 15;           // float4 within row
    float4 v = *(const float4*)(src + (size_t)i * DIM + j4 * 4);
    tile[i][j4 * 4 + 0] = v.x; tile[i][j4 * 4 + 1] = v.y;
    tile[i][j4 * 4 + 2] = v.z; tile[i][j4 * 4 + 3] = v.w;
  }
  __syncthreads();
  unsigned short* dst = WT + (((size_t)e * DIM) + (size_t)nb * 64) * DIM + kb * 64;
  #pragma unroll
  for (int p = 0; p < 4; ++p) {
    int q = p * 256 + t;
    int j = q >> 4;            // n-row 0..63
    int i4 = q & 15;           // k float4
    ushort4 o;
    o.x = f2bf(tile[i4 * 4 + 0][j]);
    o.y = f2bf(tile[i4 * 4 + 1][j]);
    o.z = f2bf(tile[i4 * 4 + 2][j]);
    o.w = f2bf(tile[i4 * 4 + 3][j]);
    *(ushort4*)(dst + (size_t)j * DIM + i4 * 4) = o;
  }
}

// -- kernel 3: grouped GEMM, m97 shape (128x128, 4 waves x 64x64), split-K, A via indirection
__global__ __launch_bounds__(256, 4) void k_moe_gemm(
    const unsigned short* __restrict__ xb,   // [N_TOK][DIM] bf16 (token order)
    const unsigned short* __restrict__ WT,   // [NEXP][DIM n][DIM k] bf16
    const int* __restrict__ sei, const int* __restrict__ ssi, const int* __restrict__ kp,
    const float* __restrict__ zbuf,
    unsigned short* __restrict__ p0,         // [NSORT][DIM] bf16 partial (k-half 0 / full)
    unsigned short* __restrict__ p1,         // [NSORT][DIM] bf16 partial (k-half 1)
    int nsl)                                 // 0: no split, 1: split-K x2
{
  __shared__ unsigned short lA[BM * BK];   // 16 KB
  __shared__ unsigned short lB[BN * BK];   // 16 KB
  __shared__ int s_sei[BM];
  __shared__ int s_ssi[BM];
  __shared__ int s_tok[BM];

  // XCD-aware bijective swizzle (nwg % 8 == 0); within an XCD chunk, (ct,half) vary
  // fastest so blocks sharing an A row-panel stay in one XCD's L2.
  const int nwg = (int)gridDim.x;            // 512 (ns=1) or 1024 (ns=2)
  const int cpx = nwg >> 3;
  const int swz = ((int)blockIdx.x & 7) * cpx + ((int)blockIdx.x >> 3);
  const int rt   = swz >> (3 + nsl);         // 0..63 row tile
  const int rem  = swz & ((8 << nsl) - 1);
  const int ct   = rem >> nsl;               // 0..7 col tile
  const int half = rem & nsl;                // k-half (0 when no split)

  const int t = threadIdx.x;
  const int lane = t & 63;
  const int w = t >> 6;                // 4 waves, 2M x 2N (64x64 each: 32 MFMA/step)
  const int wr = w >> 1;
  const int wc = w & 1;
  const int kk = kp[0];

  if (t < BM) {
    const int si = ssi[rt * BM + t];
    s_sei[t] = sei[rt * BM + t];
    s_ssi[t] = si;
    s_tok[t] = si / kk;                // source token for A-row indirection
  }
  __syncthreads();

  const int e0 = s_sei[0];
  const int e1 = s_sei[BM - 1];
  const int kshift = 4 - nsl;          // K-steps per expert pass: 16 (full) or 8 (half)
  const int nsteps = (e1 - e0 + 1) << kshift;
  const int halfbyte = half << 10;     // byte offset of this k-half within a 2KB row

  f32x4 acc[4][4];
  #pragma unroll
  for (int m = 0; m < 4; ++m)
    #pragma unroll
    for (int n = 0; n < 4; ++n)
      acc[m][n] = (f32x4){0.f, 0.f, 0.f, 0.f};

  const int g = lane >> 4;
  const int r = lane & 15;

  // staging geometry (rule 21: linear LDS dest, inverse-swizzled global source)
  // A and B are each 16 chunks of 1KB; wave owns chunks 4w..4w+3 of each
  int rA[4], kA[4];
  #pragma unroll
  for (int i = 0; i < 4; ++i) {
    int o = (4 * w + i) * 1024 + lane * 16;
    int osw = o ^ (((o >> 7) & 7) << 4);
    rA[i] = osw >> 7; kA[i] = osw & 127;   // row 0..127, byte-in-128B-krow
  }

  // per-expert hoisted source bases (per-lane); masked A rows point at the 2KB zero page
  const char *ap[4], *bp[4];
  int ecur = 0x7fffffff;
  auto setup = [&](int e) {
    #pragma unroll
    for (int i = 0; i < 4; ++i) {
      ap[i] = (s_sei[rA[i]] == e)
          ? (const char*)(xb + (size_t)s_tok[rA[i]] * DIM) + kA[i] : (const char*)zbuf;
      bp[i] = (const char*)(WT + (((size_t)e * DIM) + ct * BN + rA[i]) * DIM) + kA[i];
    }
  };
  auto stage = [&](int s) {
    const int e = e0 + (s >> kshift);
    if (e != ecur) { ecur = e; setup(e); }   // wave-uniform, fires ~1.1x per block
    const int kt = s & ((1 << kshift) - 1);
    const int koff = halfbyte + kt * 128;    // max 1920; zbuf 2KB covers +kA+16
    #pragma unroll
    for (int i = 0; i < 4; ++i) {
      gload16((char*)lA + (4 * w + i) * 1024, ap[i] + koff);
      gload16((char*)lB + (4 * w + i) * 1024, bp[i] + koff);
    }
  };

  for (int s = 0; s < nsteps; ++s) {
    stage(s);
    __syncthreads();   // vmcnt(0) drain + barrier (cross-block TLP hides it at 4 blk/CU)
    #pragma unroll
    for (int kh = 0; kh < 2; ++kh) {
      const int kbyte = (kh * 32 + 8 * g) * 2;   // same k-slot for A and B (positional symmetry)
      bfrag af[4], bfv[4];
      #pragma unroll
      for (int m = 0; m < 4; ++m) {
        const int row = wr * 64 + m * 16 + r;
        int o = (row << 7) + kbyte;
        o ^= ((row & 7) << 4);
        af[m] = *(const bfrag*)((const char*)lA + o);
      }
      #pragma unroll
      for (int n = 0; n < 4; ++n) {
        const int nn = wc * 64 + n * 16 + r;
        int o = (nn << 7) + kbyte;
        o ^= ((nn & 7) << 4);
        bfv[n] = *(const bfrag*)((const char*)lB + o);
      }
      #pragma unroll
      for (int m = 0; m < 4; ++m)
        #pragma unroll
        for (int n = 0; n < 4; ++n)
          acc[m][n] = __builtin_amdgcn_mfma_f32_16x16x32_bf16(af[m], bfv[n], acc[m][n], 0, 0, 0);
    }
    __syncthreads();   // compute done before next stage overwrites LDS
  }

  // epilogue: C/D map col = lane&15, row = (lane>>4)*4 + reg; scatter rows by ssi (bf16)
  unsigned short* pd = half ? p1 : p0;
  #pragma unroll
  for (int m = 0; m < 4; ++m) {
    #pragma unroll
    for (int q = 0; q < 4; ++q) {
      const int rl = wr * 64 + m * 16 + g * 4 + q;
      const int orow = s_ssi[rl];
      unsigned short* od = pd + (size_t)orow * DIM + ct * BN + wc * 64 + r;
      #pragma unroll
      for (int n = 0; n < 4; ++n)
        od[n * 16] = f2bf(acc[m][n][q]);
    }
  }
}

// ---------------- kernel 4: gate-weighted combine of split partials -> fp32 out ---------
__global__ __launch_bounds__(256) void k_combine(
    const unsigned short* __restrict__ p0, const unsigned short* __restrict__ p1,
    const float* __restrict__ gates, const int* __restrict__ kp, int nsl,
    float* __restrict__ out)
{
  const int tk = blockIdx.x;     // token
  const int t = threadIdx.x;     // 256 threads x 4 floats
  const int kk = kp[0];
  float4 o = {0.f, 0.f, 0.f, 0.f};
  for (int s = 0; s < kk; ++s) {
    const float gte = gates[tk * kk + s];
    const size_t base = ((size_t)tk * kk + s) * DIM;
    ushort4 a = ((const ushort4*)(p0 + base))[t];
    float4 v = {bf2f(a.x), bf2f(a.y), bf2f(a.z), bf2f(a.w)};
    if (nsl) {
      ushort4 b = ((const ushort4*)(p1 + base))[t];
      v.x += bf2f(b.x); v.y += bf2f(b.y); v.z += bf2f(b.z); v.w += bf2f(b.w);
    }
    o.x += gte * v.x; o.y += gte * v.y; o.z += gte * v.z; o.w += gte * v.w;
  }
  ((float4*)(out + (size_t)tk * DIM))[t] = o;
}

extern "C" void kernel_launch(void* const* d_in, const int* in_sizes, int n_in,
                              void* d_out, int out_size, void* d_ws, size_t ws_size,
                              hipStream_t stream)
{
  const float* x     = (const float*)d_in[0];
  const float* W     = (const float*)d_in[1];
  const float* gates = (const float*)d_in[2];
  const int* kp      = (const int*)d_in[3];
  const int* sei     = (const int*)d_in[4];
  const int* ssi     = (const int*)d_in[5];
  // d_in[6] padded_block_idxs, d_in[7] expert_offsets: not needed (masked pass loop)

  const size_t MB = 1024 * 1024;
  // split-K x2 needs 56MB+4KB scratch; fall back to single-K (40MB+4KB) if tight
  int ns = (ws_size >= 56 * MB + 4096) ? 2 : 1;
  if (ws_size < (size_t)(24 + 16 * ns) * MB + 4096) return;

  char* ws = (char*)d_ws;
  unsigned short* xb = (unsigned short*)(ws);                // 8  MB: bf16 x (token order)
  unsigned short* WT = (unsigned short*)(ws + 8 * MB);       // 16 MB: bf16 W^T
  unsigned short* p0 = (unsigned short*)(ws + 24 * MB);      // 16 MB: partial (half 0 / full)
  unsigned short* p1 = (unsigned short*)(ws + 40 * MB);      // 16 MB: partial (half 1)
  float* zbuf        = (float*)(ws + (size_t)(24 + 16 * ns) * MB);   // 2 KB zero page

  k_prep<<<N_TOK * DIM / (256 * 8), 256, 0, stream>>>(x, xb, zbuf);
  k_transp_w<<<dim3(16, 16, 8), 256, 0, stream>>>(W, WT);
  k_moe_gemm<<<(NSORT / BM) * (DIM / BN) * ns, 256, 0, stream>>>(
      xb, WT, sei, ssi, kp, zbuf, p0, p1, ns - 1);
  k_combine<<<N_TOK, 256, 0, stream>>>(p0, p1, gates, kp, ns - 1, (float*)d_out);
}